// Round 10
// baseline (323.066 us; speedup 1.0000x reference)
//
#include <hip/hip_runtime.h>

#define N_NODES 50000
#define N_EDGES 800000
#define HID 128
#define NB 256   // node buckets
#define NPB 196  // nodes per bucket
#define TP 136   // T1 LDS row stride in shorts

typedef __attribute__((ext_vector_type(8))) _Float16 f16x8;
typedef __attribute__((ext_vector_type(2))) _Float16 h2v;
typedef __attribute__((ext_vector_type(2))) __fp16 fp16v2;
typedef __attribute__((ext_vector_type(4))) float f32x4;
typedef __attribute__((ext_vector_type(2))) float f32x2;

__device__ __forceinline__ unsigned pkh(float a, float b) {
  union { fp16v2 h; unsigned u; } c;
  c.h = __builtin_amdgcn_cvt_pkrtz(a, b);
  return c.u;
}
__device__ __forceinline__ h2v u2h(unsigned u) {
  union { unsigned u; h2v h; } c;
  c.u = u;
  return c.h;
}
__device__ __forceinline__ f32x2 unpkh(unsigned u) {
  h2v h = u2h(u);
  f32x2 r;
  r[0] = (float)h[0];
  r[1] = (float)h[1];
  return r;
}
__device__ __forceinline__ short f2hs(float f) {
  union { _Float16 h; short s; } c;
  c.h = (_Float16)f;
  return c.s;
}
// packed fp16: relu(a+b), returns packed pair (v_pk_add_f16 + v_pk_max_f16)
__device__ __forceinline__ unsigned hrelu_add(unsigned a, unsigned b) {
  h2v r = u2h(a) + u2h(b);
  h2v z = {(_Float16)0.f, (_Float16)0.f};
  r = __builtin_elementwise_max(r, z);
  union { h2v h; unsigned u; } c;
  c.h = r;
  return c.u;
}

// ================= CSR build (dst side only; out-degree via global atomics) ====

__global__ __launch_bounds__(256) void p1_hist_kernel(
    const int* __restrict__ src, const int* __restrict__ dst,
    int* __restrict__ bcnt_d, int* __restrict__ deg_out) {
  __shared__ int hd[NB];
  int t = threadIdx.x;
  hd[t] = 0;
  __syncthreads();
  for (int e = blockIdx.x * 256 + t; e < N_EDGES; e += gridDim.x * 256) {
    atomicAdd(&hd[dst[e] / NPB], 1);
    atomicAdd(&deg_out[src[e]], 1);  // 200 KB counter array, L2-resident
  }
  __syncthreads();
  if (hd[t]) atomicAdd(&bcnt_d[t], hd[t]);
}

// block 0: dst scan.  blocks 1..64: fp16 weight transposes (+w2h, h1b zero row).
// blocks 65..260: norm_out from deg_out counters.
__global__ void p2_scan_prep_kernel(
    const int* __restrict__ bcnt_d, int* __restrict__ bofs_d,
    int* __restrict__ cur_d, const int* __restrict__ deg_out,
    float* __restrict__ norm_out,
    const float* __restrict__ Wa, const float* __restrict__ Wb,
    const float* __restrict__ Wc, const float* __restrict__ w2f,
    short* __restrict__ Wta, short* __restrict__ Wtb, short* __restrict__ Wtc,
    unsigned* __restrict__ w2h, short* __restrict__ h1bz) {
  int b = blockIdx.x;
  if (b >= 65) {
    int n = (b - 65) * 256 + threadIdx.x;
    if (n < N_NODES) {
      int v = deg_out[n];
      norm_out[n] = rsqrtf((float)(v < 1 ? 1 : v));
    }
    return;
  }
  if (b > 0) {
    int t = (b - 1) * 256 + threadIdx.x;
    if (t < HID * HID) {
      int k = t >> 7, n = t & 127;
      Wta[n * HID + k] = f2hs(Wa[t]);
      Wtb[n * HID + k] = f2hs(Wb[t]);
      Wtc[n * HID + k] = f2hs(Wc[t]);
    }
    if (b == 1) {
      int t0 = threadIdx.x;
      if (t0 < 64) {
        w2h[t0] = pkh(w2f[2 * t0], w2f[2 * t0 + 1]);
      } else if (t0 < 128) {
        ((unsigned*)h1bz)[t0 - 64] = 0u;
      }
    }
    return;
  }
  __shared__ int s[NB];
  int t = threadIdx.x;
  int v = bcnt_d[t];
  s[t] = v;
  __syncthreads();
  for (int o = 1; o < NB; o <<= 1) {
    int x = (t >= o) ? s[t - o] : 0;
    __syncthreads();
    s[t] += x;
    __syncthreads();
  }
  int ofs = s[t] - v;
  bofs_d[t] = ofs; cur_d[t] = ofs;
  if (t == NB - 1) bofs_d[NB] = s[t];
}

// dst scatter: one pass over edges, one LDS histogram
__global__ __launch_bounds__(256) void p3_scatter_kernel(
    const int* __restrict__ src, const int* __restrict__ dst,
    int* __restrict__ cur_d, int2* __restrict__ sdst) {
  __shared__ int bcd[NB], bbd[NB];
  int t = threadIdx.x;
  int base = blockIdx.x * 2048;
  bcd[t] = 0;
  __syncthreads();
  int mybd[8], myrd[8], mys[8], myp[8];
#pragma unroll
  for (int u = 0; u < 8; ++u) {
    int e = base + u * 256 + t;
    mybd[u] = -1;
    if (e < N_EDGES) {
      int s = src[e], d = dst[e];
      int bd = d / NPB;
      mybd[u] = bd;
      myrd[u] = atomicAdd(&bcd[bd], 1);
      mys[u] = s;
      myp[u] = ((d - bd * NPB) << 20) | e;
    }
  }
  __syncthreads();
  {
    int cd = bcd[t];
    if (cd) bbd[t] = atomicAdd(&cur_d[t], cd);
  }
  __syncthreads();
#pragma unroll
  for (int u = 0; u < 8; ++u) {
    if (mybd[u] >= 0) {
      sdst[bbd[mybd[u]] + myrd[u]] = make_int2(mys[u], myp[u]);
    }
  }
}

// p4: per-bucket CSR build (row_ofs, norm_in, csr_src/eid/dst)
__global__ __launch_bounds__(256) void p4_kernel(
    const int2* __restrict__ sdst, const int* __restrict__ bofs_d,
    int* __restrict__ row_ofs, float* __restrict__ norm_in,
    int* __restrict__ csr_src, int* __restrict__ csr_eid,
    int* __restrict__ csr_dst) {
  __shared__ int hc[NB], sc[NB], cur[NB];
  int t = threadIdx.x;
  int b = blockIdx.x;
  int base = bofs_d[b], cnt = bofs_d[b + 1] - base;
  hc[t] = 0;
  __syncthreads();
  for (int i = t; i < cnt; i += 256) atomicAdd(&hc[sdst[base + i].y >> 20], 1);
  __syncthreads();
  int v = hc[t];
  sc[t] = v;
  __syncthreads();
  for (int o = 1; o < NB; o <<= 1) {
    int x = (t >= o) ? sc[t - o] : 0;
    __syncthreads();
    sc[t] += x;
    __syncthreads();
  }
  int ofs = sc[t] - v;
  int node = b * NPB + t;
  if (t < NPB && node < N_NODES) {
    row_ofs[node] = base + ofs;
    norm_in[node] = rsqrtf((float)(v < 1 ? 1 : v));
  }
  cur[t] = base + ofs;
  if (b == 0 && t == 0) row_ofs[N_NODES] = N_EDGES;
  __syncthreads();
  for (int i = t; i < cnt; i += 256) {
    int2 e = sdst[base + i];
    int loc = e.y >> 20;
    int pos = atomicAdd(&cur[loc], 1);
    csr_src[pos] = e.x;
    csr_eid[pos] = e.y & 0xFFFFF;
    csr_dst[pos] = b * NPB + loc;
  }
}

// ================= model kernels =================

__global__ __launch_bounds__(256) void agg4_kernel(
    const float4* __restrict__ nf4, const float* __restrict__ no_,
    const int* __restrict__ csr_src, const int* __restrict__ row_ofs,
    float4* __restrict__ agg4, float* __restrict__ sno) {
  int wid = (blockIdx.x * blockDim.x + threadIdx.x) >> 6;
  int lane = threadIdx.x & 63;
  int g = lane >> 4, l = lane & 15;
  int v = wid * 4 + g;
  if (v >= N_NODES) return;
  int beg = row_ofs[v], end = row_ofs[v + 1];
  float ax = 0.f, ay = 0.f, az = 0.f, aw = 0.f, sn = 0.f;
  for (int i = beg + l; i < end; i += 16) {
    int s = csr_src[i];
    float w = no_[s];
    float4 n = nf4[s];
    ax += n.x * w; ay += n.y * w; az += n.z * w; aw += n.w * w;
    sn += w;
  }
#pragma unroll
  for (int o = 1; o < 16; o <<= 1) {
    ax += __shfl_xor(ax, o, 16);
    ay += __shfl_xor(ay, o, 16);
    az += __shfl_xor(az, o, 16);
    aw += __shfl_xor(aw, o, 16);
    sn += __shfl_xor(sn, o, 16);
  }
  if (l == 0) {
    agg4[v] = make_float4(ax, ay, az, aw);
    sno[v] = sn;
  }
}

// layer-1 fully fused via MFMA (fp16): expand 4->128 per-lane in B-frag layout, no LDS.
__global__ __launch_bounds__(256) void gemm_l1_mfma(
    const float4* __restrict__ agg4, const float* __restrict__ sno,
    const float* __restrict__ ni_, const float* __restrict__ no_,
    const float* __restrict__ Wn, const float* __restrict__ bn,
    const short* __restrict__ Wt0, const float* __restrict__ b0,
    short* __restrict__ h1b, int nrows) {
  int t = threadIdx.x;
  int w = t >> 6, lane = t & 63;
  int m16 = lane & 15, quad = lane >> 4;
  int v0 = blockIdx.x * 64;
  int row = v0 + w * 16 + m16;
  bool rvalid = row < nrows;
  int rc = rvalid ? row : (nrows - 1);
  float4 a = agg4[rc];
  float sn = sno[rc], nin = ni_[rc];

  f16x8 xfr[4];
#pragma unroll
  for (int kc = 0; kc < 4; ++kc) {
    union { unsigned u[4]; f16x8 v; } cv;
#pragma unroll
    for (int jj = 0; jj < 4; ++jj) {
      int k0 = kc * 32 + quad * 8 + jj * 2;
      float x0 = (a.x * Wn[k0] + a.y * Wn[HID + k0] + a.z * Wn[2 * HID + k0] +
                  a.w * Wn[3 * HID + k0] + bn[k0] * sn) * nin;
      int k1 = k0 + 1;
      float x1 = (a.x * Wn[k1] + a.y * Wn[HID + k1] + a.z * Wn[2 * HID + k1] +
                  a.w * Wn[3 * HID + k1] + bn[k1] * sn) * nin;
      cv.u[jj] = pkh(x0, x1);
    }
    xfr[kc] = cv.v;
  }
  f32x4 acc[8];
#pragma unroll
  for (int nt = 0; nt < 8; ++nt) {
    acc[nt][0] = 0.f; acc[nt][1] = 0.f; acc[nt][2] = 0.f; acc[nt][3] = 0.f;
  }
#pragma unroll
  for (int nt = 0; nt < 8; ++nt) {
    const f16x8* Wr = (const f16x8*)(Wt0 + (size_t)(nt * 16 + m16) * HID);
#pragma unroll
    for (int kc = 0; kc < 4; ++kc)
      acc[nt] = __builtin_amdgcn_mfma_f32_16x16x32_f16(Wr[kc * 4 + quad], xfr[kc],
                                                       acc[nt], 0, 0, 0);
  }
  if (rvalid) {
    float nov = no_[row];
#pragma unroll
    for (int nt = 0; nt < 8; ++nt) {
      int nb = nt * 16 + quad * 4;
      float4 bv = *(const float4*)&b0[nb];
      float r0 = fmaxf(acc[nt][0] + bv.x, 0.f) * nov;
      float r1 = fmaxf(acc[nt][1] + bv.y, 0.f) * nov;
      float r2 = fmaxf(acc[nt][2] + bv.z, 0.f) * nov;
      float r3 = fmaxf(acc[nt][3] + bv.w, 0.f) * nov;
      uint2 pk;
      pk.x = pkh(r0, r1);
      pk.y = pkh(r2, r3);
      *(uint2*)(h1b + (size_t)row * HID + nb) = pk;
    }
  }
}

// layer-2 aggregate: fp16 gathers, zero-row for invalid slots, packed f32x2 adds
__global__ __launch_bounds__(256) void aggregate_kernel(
    const uint4* __restrict__ hb, const int* __restrict__ row_ofs,
    const int* __restrict__ csr_src, const float* __restrict__ ni_,
    uint4* __restrict__ Ab) {
  int v = (blockIdx.x * blockDim.x + threadIdx.x) >> 6;
  int lane = threadIdx.x & 63;
  if (v >= N_NODES) return;
  int beg = row_ofs[v], end = row_ofs[v + 1];
  int g = lane >> 4, l = lane & 15;
  f32x2 acc2[4];
#pragma unroll
  for (int j = 0; j < 4; ++j) acc2[j] = (f32x2){0.f, 0.f};
  for (int i = beg; i < end; i += 16) {
    int ss[4];
#pragma unroll
    for (int u = 0; u < 4; ++u) {
      int ii = i + 4 * u + g;
      ss[u] = (ii < end) ? csr_src[ii] : N_NODES;  // zero row
    }
    uint4 X[4];
#pragma unroll
    for (int u = 0; u < 4; ++u) X[u] = hb[(size_t)ss[u] * 16 + l];
#pragma unroll
    for (int u = 0; u < 4; ++u) {
      acc2[0] += unpkh(X[u].x);
      acc2[1] += unpkh(X[u].y);
      acc2[2] += unpkh(X[u].z);
      acc2[3] += unpkh(X[u].w);
    }
  }
#pragma unroll
  for (int j = 0; j < 4; ++j) {
    acc2[j][0] += __shfl_xor(acc2[j][0], 16, 64);
    acc2[j][0] += __shfl_xor(acc2[j][0], 32, 64);
    acc2[j][1] += __shfl_xor(acc2[j][1], 16, 64);
    acc2[j][1] += __shfl_xor(acc2[j][1], 32, 64);
  }
  if (g == 0) {
    float n = ni_[v];
    uint4 pk;
    pk.x = pkh(acc2[0][0] * n, acc2[0][1] * n);
    pk.y = pkh(acc2[1][0] * n, acc2[1][1] * n);
    pk.z = pkh(acc2[2][0] * n, acc2[2][1] * n);
    pk.w = pkh(acc2[3][0] * n, acc2[3][1] * n);
    Ab[(size_t)v * 16 + l] = pk;
  }
}

// fused layer-2 GEMM + output GEMM via MFMA (fp16); epilogue adds 0.5*b1 so the
// edge kernel sees y_s + y_d = edge_h @ W1 + b1 with no bias work.
__global__ __launch_bounds__(256) void gemm_dual_mfma(
    const short* __restrict__ Ab, const short* __restrict__ Wt0,
    const float* __restrict__ b0, const short* __restrict__ Wt1,
    const float* __restrict__ b1o, short* __restrict__ yb, int nrows) {
  __shared__ short T1s[4][16 * TP];
  int t = threadIdx.x;
  int w = t >> 6, lane = t & 63;
  int m16 = lane & 15, quad = lane >> 4;
  int v0 = blockIdx.x * 64;
  int row = v0 + w * 16 + m16;
  bool rvalid = row < nrows;
  int rc = rvalid ? row : (nrows - 1);

  f16x8 xfr[4];
  {
    const f16x8* Ar = (const f16x8*)(Ab + (size_t)rc * HID);
#pragma unroll
    for (int kc = 0; kc < 4; ++kc) xfr[kc] = Ar[kc * 4 + quad];
  }
  f32x4 acc[8];
#pragma unroll
  for (int nt = 0; nt < 8; ++nt) {
    acc[nt][0] = 0.f; acc[nt][1] = 0.f; acc[nt][2] = 0.f; acc[nt][3] = 0.f;
  }
#pragma unroll
  for (int nt = 0; nt < 8; ++nt) {
    const f16x8* Wr = (const f16x8*)(Wt0 + (size_t)(nt * 16 + m16) * HID);
#pragma unroll
    for (int kc = 0; kc < 4; ++kc)
      acc[nt] = __builtin_amdgcn_mfma_f32_16x16x32_f16(Wr[kc * 4 + quad], xfr[kc],
                                                       acc[nt], 0, 0, 0);
  }
  short* T1w = &T1s[w][0];
#pragma unroll
  for (int nt = 0; nt < 8; ++nt) {
    int nb = nt * 16 + quad * 4;
    float4 bv = *(const float4*)&b0[nb];
    float r0 = fmaxf(acc[nt][0] + bv.x, 0.f);
    float r1 = fmaxf(acc[nt][1] + bv.y, 0.f);
    float r2 = fmaxf(acc[nt][2] + bv.z, 0.f);
    float r3 = fmaxf(acc[nt][3] + bv.w, 0.f);
    uint2 pk;
    pk.x = pkh(r0, r1);
    pk.y = pkh(r2, r3);
    *(uint2*)&T1w[m16 * TP + nb] = pk;
    acc[nt][0] = 0.f; acc[nt][1] = 0.f; acc[nt][2] = 0.f; acc[nt][3] = 0.f;
  }
  __syncthreads();
  f16x8 tfr[4];
#pragma unroll
  for (int kc = 0; kc < 4; ++kc)
    tfr[kc] = *(const f16x8*)&T1w[m16 * TP + kc * 32 + quad * 8];
#pragma unroll
  for (int nt = 0; nt < 8; ++nt) {
    const f16x8* Wr = (const f16x8*)(Wt1 + (size_t)(nt * 16 + m16) * HID);
#pragma unroll
    for (int kc = 0; kc < 4; ++kc)
      acc[nt] = __builtin_amdgcn_mfma_f32_16x16x32_f16(Wr[kc * 4 + quad], tfr[kc],
                                                       acc[nt], 0, 0, 0);
  }
  if (rvalid) {
#pragma unroll
    for (int nt = 0; nt < 8; ++nt) {
      int nb = nt * 16 + quad * 4;
      float4 bv = *(const float4*)&b1o[nb];
      uint2 pk;
      pk.x = pkh(acc[nt][0] + 0.5f * bv.x, acc[nt][1] + 0.5f * bv.y);
      pk.y = pkh(acc[nt][2] + 0.5f * bv.z, acc[nt][3] + 0.5f * bv.w);
      *(uint2*)(yb + (size_t)row * HID + nb) = pk;
    }
  }
}

// edge output via MFMA (round-4 form): wave handles 64 edges (4 groups of 16).
// Lane (m16=edge, quad=k-chunk): loads one uint4 (8 fp16) of y[src] and y[dst];
// 4 quads/edge share one 64B line -> 4 line-lookups/edge. relu(ys+yd) via
// v_pk_add/v_pk_max feeds the MFMA A-fragment, B = w2 replicated across cols.
__global__ __launch_bounds__(256) void edge_out_mfma(
    const int* __restrict__ csr_src, const int* __restrict__ csr_dst,
    const int* __restrict__ csr_eid, const short* __restrict__ yb,
    const short* __restrict__ w2h16, const float* __restrict__ b2,
    float* __restrict__ out) {
  int t = threadIdx.x;
  int wv = (blockIdx.x * 256 + t) >> 6;  // global wave id
  int lane = t & 63;
  int m16 = lane & 15, quad = lane >> 4;
  int e0 = wv * 64;
  if (e0 >= N_EDGES) return;
  float ob2 = b2[0];

  f16x8 bfr[4];
#pragma unroll
  for (int kb = 0; kb < 4; ++kb)
    bfr[kb] = *(const f16x8*)(w2h16 + kb * 32 + quad * 8);

#pragma unroll
  for (int g = 0; g < 4; ++g) {
    int e = e0 + g * 16 + m16;
    int s = csr_src[e], d = csr_dst[e];
    const short* ys = yb + (size_t)s * HID + quad * 8;
    const short* yd = yb + (size_t)d * HID + quad * 8;
    f32x4 acc = {0.f, 0.f, 0.f, 0.f};
#pragma unroll
    for (int kb = 0; kb < 4; ++kb) {
      uint4 a = *(const uint4*)(ys + kb * 32);
      uint4 b = *(const uint4*)(yd + kb * 32);
      union { uint4 u; f16x8 v; } r;
      r.u.x = hrelu_add(a.x, b.x);
      r.u.y = hrelu_add(a.y, b.y);
      r.u.z = hrelu_add(a.z, b.z);
      r.u.w = hrelu_add(a.w, b.w);
      acc = __builtin_amdgcn_mfma_f32_16x16x32_f16(r.v, bfr[kb], acc, 0, 0, 0);
    }
    if (m16 == 0) {
      int eb = e0 + g * 16 + quad * 4;
#pragma unroll
      for (int r = 0; r < 4; ++r) {
        out[csr_eid[eb + r]] = acc[r] + ob2;
      }
    }
  }
}

extern "C" void kernel_launch(void* const* d_in, const int* in_sizes, int n_in,
                              void* d_out, int out_size, void* d_ws, size_t ws_size,
                              hipStream_t stream) {
  const float* node_feats = (const float*)d_in[1];
  const int*   src        = (const int*)d_in[2];
  const int*   dst        = (const int*)d_in[3];
  const float* W_nemb     = (const float*)d_in[6];
  const float* b_nemb     = (const float*)d_in[7];
  const float* gnn_W      = (const float*)d_in[8];
  const float* gnn_b      = (const float*)d_in[9];
  const float* out_W1     = (const float*)d_in[10];
  const float* out_b1     = (const float*)d_in[11];
  const float* out_W2     = (const float*)d_in[12];
  const float* out_b2     = (const float*)d_in[13];
  float* out = (float*)d_out;

  size_t off = 0;
  char* base = (char*)d_ws;
  auto alloc = [&](size_t nbytes) -> char* {
    off = (off + 255) & ~(size_t)255;
    char* p = base + off;
    off += nbytes;
    return p;
  };
  // bcnt_d and deg_out contiguous -> single memset
  int*    bcnt_d   = (int*)alloc((NB + N_NODES) * 4);
  int*    deg_out  = bcnt_d + NB;
  int*    bofs_d   = (int*)alloc((NB + 1) * 4);
  int*    cur_d    = (int*)alloc(NB * 4);
  float*  norm_out = (float*)alloc(N_NODES * 4);
  float*  norm_in  = (float*)alloc(N_NODES * 4);
  int*    row_ofs  = (int*)alloc((N_NODES + 1) * 4);
  int*    csr_src  = (int*)alloc((size_t)N_EDGES * 4);
  int*    csr_eid  = (int*)alloc((size_t)N_EDGES * 4);
  int*    csr_dst  = (int*)alloc((size_t)N_EDGES * 4);
  float4* agg4     = (float4*)alloc((size_t)N_NODES * 16);
  float*  sno      = (float*)alloc(N_NODES * 4);
  short*  Wta      = (short*)alloc((size_t)HID * HID * 2);  // fp16 W_l1^T
  short*  Wtb      = (short*)alloc((size_t)HID * HID * 2);  // fp16 W_l2^T
  short*  Wtc      = (short*)alloc((size_t)HID * HID * 2);  // fp16 out_W1^T
  unsigned* w2h    = (unsigned*)alloc(64 * 4);              // fp16 out_W2 packed
  short*  h1b      = (short*)alloc((size_t)(N_NODES + 1) * HID * 2);  // +zero row
  short*  Ab       = (short*)alloc((size_t)N_NODES * HID * 2);
  short*  ybs      = (short*)alloc((size_t)N_NODES * HID * 2);
  int2*   sdst     = (int2*)Ab;    // staging alias, consumed by p4 before Ab written
  (void)ws_size; (void)n_in; (void)in_sizes; (void)out_size;

  (void)hipMemsetAsync(bcnt_d, 0, (NB + N_NODES) * 4, stream);
  p1_hist_kernel<<<128, 256, 0, stream>>>(src, dst, bcnt_d, deg_out);
  p2_scan_prep_kernel<<<65 + (N_NODES + 255) / 256, 256, 0, stream>>>(
      bcnt_d, bofs_d, cur_d, deg_out, norm_out,
      gnn_W, gnn_W + (size_t)HID * HID, out_W1, out_W2,
      Wta, Wtb, Wtc, w2h, h1b + (size_t)N_NODES * HID);
  p3_scatter_kernel<<<(N_EDGES + 2047) / 2048, 256, 0, stream>>>(
      src, dst, cur_d, sdst);
  p4_kernel<<<NB, 256, 0, stream>>>(
      sdst, bofs_d, row_ofs, norm_in, csr_src, csr_eid, csr_dst);

  agg4_kernel<<<(N_NODES * 16 + 255) / 256, 256, 0, stream>>>(
      (const float4*)node_feats, norm_out, csr_src, row_ofs, agg4, sno);
  gemm_l1_mfma<<<(N_NODES + 63) / 64, 256, 0, stream>>>(
      agg4, sno, norm_in, norm_out, W_nemb, b_nemb, Wta, gnn_b, h1b, N_NODES);

  aggregate_kernel<<<(N_NODES * 64 + 255) / 256, 256, 0, stream>>>(
      (const uint4*)h1b, row_ofs, csr_src, norm_in, (uint4*)Ab);

  gemm_dual_mfma<<<(N_NODES + 63) / 64, 256, 0, stream>>>(
      Ab, Wtb, gnn_b + HID, Wtc, out_b1, ybs, N_NODES);

  edge_out_mfma<<<(N_EDGES / 64 + 3) / 4, 256, 0, stream>>>(
      csr_src, csr_dst, csr_eid, ybs, (const short*)w2h, out_b2, out);
}

// Round 11
// 307.979 us; speedup vs baseline: 1.0490x; 1.0490x over previous
//
#include <hip/hip_runtime.h>

#define N_NODES 50000
#define N_EDGES 800000
#define HID 128
#define NB 256   // node buckets
#define NPB 196  // nodes per bucket
#define TP 136   // T1 LDS row stride in shorts
#define P1G 128  // p1 grid (fixed; p2 sums exactly this many partials)

typedef __attribute__((ext_vector_type(8))) _Float16 f16x8;
typedef __attribute__((ext_vector_type(2))) _Float16 h2v;
typedef __attribute__((ext_vector_type(2))) __fp16 fp16v2;
typedef __attribute__((ext_vector_type(4))) float f32x4;
typedef __attribute__((ext_vector_type(2))) float f32x2;

__device__ __forceinline__ unsigned pkh(float a, float b) {
  union { fp16v2 h; unsigned u; } c;
  c.h = __builtin_amdgcn_cvt_pkrtz(a, b);
  return c.u;
}
__device__ __forceinline__ h2v u2h(unsigned u) {
  union { unsigned u; h2v h; } c;
  c.u = u;
  return c.h;
}
__device__ __forceinline__ f32x2 unpkh(unsigned u) {
  h2v h = u2h(u);
  f32x2 r;
  r[0] = (float)h[0];
  r[1] = (float)h[1];
  return r;
}
__device__ __forceinline__ short f2hs(float f) {
  union { _Float16 h; short s; } c;
  c.h = (_Float16)f;
  return c.s;
}
// packed fp16: relu(a+b), returns packed pair (v_pk_add_f16 + v_pk_max_f16)
__device__ __forceinline__ unsigned hrelu_add(unsigned a, unsigned b) {
  h2v r = u2h(a) + u2h(b);
  h2v z = {(_Float16)0.f, (_Float16)0.f};
  r = __builtin_elementwise_max(r, z);
  union { h2v h; unsigned u; } c;
  c.h = r;
  return c.u;
}

// ================= bucketed CSR build =================

// per-block histogram partials (no atomics, no memset needed)
__global__ __launch_bounds__(256) void p1_hist_kernel(
    const int* __restrict__ src, const int* __restrict__ dst,
    int* __restrict__ part_d, int* __restrict__ part_s) {
  __shared__ int hd[NB], hs[NB];
  int t = threadIdx.x;
  hd[t] = 0; hs[t] = 0;
  __syncthreads();
  for (int e = blockIdx.x * 256 + t; e < N_EDGES; e += gridDim.x * 256) {
    atomicAdd(&hd[dst[e] / NPB], 1);
    atomicAdd(&hs[src[e] / NPB], 1);
  }
  __syncthreads();
  part_d[blockIdx.x * NB + t] = hd[t];
  part_s[blockIdx.x * NB + t] = hs[t];
}

// block 0: partial-sum + dual wave-scan.  blocks 1..64: fp16 weight transposes
// + w2h pack + h1b zero row
__global__ void p2_scan_prep_kernel(
    const int* __restrict__ part_d, const int* __restrict__ part_s,
    int* __restrict__ bofs_d, int* __restrict__ bofs_s,
    int* __restrict__ cur_d, int* __restrict__ cur_s,
    const float* __restrict__ Wa, const float* __restrict__ Wb,
    const float* __restrict__ Wc, const float* __restrict__ w2f,
    short* __restrict__ Wta, short* __restrict__ Wtb, short* __restrict__ Wtc,
    unsigned* __restrict__ w2h, short* __restrict__ h1bz) {
  int b = blockIdx.x;
  if (b > 0) {
    int t = (b - 1) * 256 + threadIdx.x;
    if (t < HID * HID) {
      int k = t >> 7, n = t & 127;
      Wta[n * HID + k] = f2hs(Wa[t]);
      Wtb[n * HID + k] = f2hs(Wb[t]);
      Wtc[n * HID + k] = f2hs(Wc[t]);
    }
    if (b == 1) {
      int t0 = threadIdx.x;
      if (t0 < 64) {
        w2h[t0] = pkh(w2f[2 * t0], w2f[2 * t0 + 1]);
      } else if (t0 < 128) {
        ((unsigned*)h1bz)[t0 - 64] = 0u;
      }
    }
    return;
  }
  __shared__ int ws[4];
  int t = threadIdx.x, lane = t & 63, w = t >> 6;
  // ---- dst side ----
  int v = 0;
  for (int p = 0; p < P1G; ++p) v += part_d[p * NB + t];
  int x = v;
#pragma unroll
  for (int o = 1; o < 64; o <<= 1) {
    int y = __shfl_up(x, o, 64);
    if (lane >= o) x += y;
  }
  if (lane == 63) ws[w] = x;
  __syncthreads();
  int pre = 0;
#pragma unroll
  for (int j = 0; j < 4; ++j)
    if (j < w) pre += ws[j];
  int incl = pre + x;
  int ofs = incl - v;
  bofs_d[t] = ofs; cur_d[t] = ofs;
  if (t == NB - 1) bofs_d[NB] = incl;
  __syncthreads();
  // ---- src side ----
  v = 0;
  for (int p = 0; p < P1G; ++p) v += part_s[p * NB + t];
  x = v;
#pragma unroll
  for (int o = 1; o < 64; o <<= 1) {
    int y = __shfl_up(x, o, 64);
    if (lane >= o) x += y;
  }
  if (lane == 63) ws[w] = x;
  __syncthreads();
  pre = 0;
#pragma unroll
  for (int j = 0; j < 4; ++j)
    if (j < w) pre += ws[j];
  incl = pre + x;
  ofs = incl - v;
  bofs_s[t] = ofs; cur_s[t] = ofs;
  if (t == NB - 1) bofs_s[NB] = incl;
}

// fused dst+src scatter: one pass over edges, two LDS histograms
__global__ __launch_bounds__(256) void p3_scatter_both_kernel(
    const int* __restrict__ src, const int* __restrict__ dst,
    int* __restrict__ cur_d, int* __restrict__ cur_s,
    int2* __restrict__ sdst, int* __restrict__ ssrc) {
  __shared__ int bcd[NB], bbd[NB], bcs[NB], bbs[NB];
  int t = threadIdx.x;
  int base = blockIdx.x * 2048;
  bcd[t] = 0; bcs[t] = 0;
  __syncthreads();
  int mybd[8], myrd[8], mys[8], myp[8], mybs[8], myrs[8];
#pragma unroll
  for (int u = 0; u < 8; ++u) {
    int e = base + u * 256 + t;
    mybd[u] = -1;
    if (e < N_EDGES) {
      int s = src[e], d = dst[e];
      int bd = d / NPB;
      mybd[u] = bd;
      myrd[u] = atomicAdd(&bcd[bd], 1);
      mys[u] = s;
      myp[u] = ((d - bd * NPB) << 20) | e;
      int bs = s / NPB;
      mybs[u] = bs;
      myrs[u] = atomicAdd(&bcs[bs], 1);
    }
  }
  __syncthreads();
  {
    int cd = bcd[t];
    if (cd) bbd[t] = atomicAdd(&cur_d[t], cd);
    int cs = bcs[t];
    if (cs) bbs[t] = atomicAdd(&cur_s[t], cs);
  }
  __syncthreads();
#pragma unroll
  for (int u = 0; u < 8; ++u) {
    if (mybd[u] >= 0) {
      sdst[bbd[mybd[u]] + myrd[u]] = make_int2(mys[u], myp[u]);
      ssrc[bbs[mybs[u]] + myrs[u]] = mys[u];
    }
  }
}

// merged p4 (CSR build, blocks [0,NB)) + p5 (deg_out, blocks [NB,2NB))
__global__ __launch_bounds__(256) void p45_kernel(
    const int2* __restrict__ sdst, const int* __restrict__ bofs_d,
    int* __restrict__ row_ofs, float* __restrict__ norm_in,
    int* __restrict__ csr_src, int* __restrict__ csr_eid, int* __restrict__ csr_dst,
    const int* __restrict__ ssrc, const int* __restrict__ bofs_s,
    float* __restrict__ norm_out) {
  __shared__ int hc[NB], cur[NB];
  __shared__ int ws4[4];
  int t = threadIdx.x;
  if (blockIdx.x >= NB) {
    // ---- p5: out-degree ----
    int b = blockIdx.x - NB;
    int base = bofs_s[b], cnt = bofs_s[b + 1] - base;
    int lo = b * NPB;
    hc[t] = 0;
    __syncthreads();
    for (int i = t; i < cnt; i += 256) atomicAdd(&hc[ssrc[base + i] - lo], 1);
    __syncthreads();
    int node = lo + t;
    if (t < NPB && node < N_NODES) {
      int v = hc[t];
      norm_out[node] = rsqrtf((float)(v < 1 ? 1 : v));
    }
    return;
  }
  // ---- p4: CSR ----
  int b = blockIdx.x;
  int base = bofs_d[b], cnt = bofs_d[b + 1] - base;
  hc[t] = 0;
  __syncthreads();
  for (int i = t; i < cnt; i += 256) atomicAdd(&hc[sdst[base + i].y >> 20], 1);
  __syncthreads();
  int v = hc[t];
  int lane = t & 63, w = t >> 6;
  int x = v;
#pragma unroll
  for (int o = 1; o < 64; o <<= 1) {
    int y = __shfl_up(x, o, 64);
    if (lane >= o) x += y;
  }
  if (lane == 63) ws4[w] = x;
  __syncthreads();
  int pre = 0;
#pragma unroll
  for (int j = 0; j < 4; ++j)
    if (j < w) pre += ws4[j];
  int ofs = pre + x - v;
  int node = b * NPB + t;
  if (t < NPB && node < N_NODES) {
    row_ofs[node] = base + ofs;
    norm_in[node] = rsqrtf((float)(v < 1 ? 1 : v));
  }
  cur[t] = base + ofs;
  if (b == 0 && t == 0) row_ofs[N_NODES] = N_EDGES;
  __syncthreads();
  for (int i = t; i < cnt; i += 256) {
    int2 e = sdst[base + i];
    int loc = e.y >> 20;
    int pos = atomicAdd(&cur[loc], 1);
    csr_src[pos] = e.x;
    csr_eid[pos] = e.y & 0xFFFFF;
    csr_dst[pos] = b * NPB + loc;
  }
}

// ================= model kernels =================

__global__ __launch_bounds__(256) void agg4_kernel(
    const float4* __restrict__ nf4, const float* __restrict__ no_,
    const int* __restrict__ csr_src, const int* __restrict__ row_ofs,
    float4* __restrict__ agg4, float* __restrict__ sno) {
  int wid = (blockIdx.x * blockDim.x + threadIdx.x) >> 6;
  int lane = threadIdx.x & 63;
  int g = lane >> 4, l = lane & 15;
  int v = wid * 4 + g;
  if (v >= N_NODES) return;
  int beg = row_ofs[v], end = row_ofs[v + 1];
  float ax = 0.f, ay = 0.f, az = 0.f, aw = 0.f, sn = 0.f;
  for (int i = beg + l; i < end; i += 16) {
    int s = csr_src[i];
    float w = no_[s];
    float4 n = nf4[s];
    ax += n.x * w; ay += n.y * w; az += n.z * w; aw += n.w * w;
    sn += w;
  }
#pragma unroll
  for (int o = 1; o < 16; o <<= 1) {
    ax += __shfl_xor(ax, o, 16);
    ay += __shfl_xor(ay, o, 16);
    az += __shfl_xor(az, o, 16);
    aw += __shfl_xor(aw, o, 16);
    sn += __shfl_xor(sn, o, 16);
  }
  if (l == 0) {
    agg4[v] = make_float4(ax, ay, az, aw);
    sno[v] = sn;
  }
}

// layer-1 fully fused via MFMA (fp16): expand 4->128 per-lane in B-frag layout, no LDS.
__global__ __launch_bounds__(256) void gemm_l1_mfma(
    const float4* __restrict__ agg4, const float* __restrict__ sno,
    const float* __restrict__ ni_, const float* __restrict__ no_,
    const float* __restrict__ Wn, const float* __restrict__ bn,
    const short* __restrict__ Wt0, const float* __restrict__ b0,
    short* __restrict__ h1b, int nrows) {
  int t = threadIdx.x;
  int w = t >> 6, lane = t & 63;
  int m16 = lane & 15, quad = lane >> 4;
  int v0 = blockIdx.x * 64;
  int row = v0 + w * 16 + m16;
  bool rvalid = row < nrows;
  int rc = rvalid ? row : (nrows - 1);
  float4 a = agg4[rc];
  float sn = sno[rc], nin = ni_[rc];

  f16x8 xfr[4];
#pragma unroll
  for (int kc = 0; kc < 4; ++kc) {
    union { unsigned u[4]; f16x8 v; } cv;
#pragma unroll
    for (int jj = 0; jj < 4; ++jj) {
      int k0 = kc * 32 + quad * 8 + jj * 2;
      float x0 = (a.x * Wn[k0] + a.y * Wn[HID + k0] + a.z * Wn[2 * HID + k0] +
                  a.w * Wn[3 * HID + k0] + bn[k0] * sn) * nin;
      int k1 = k0 + 1;
      float x1 = (a.x * Wn[k1] + a.y * Wn[HID + k1] + a.z * Wn[2 * HID + k1] +
                  a.w * Wn[3 * HID + k1] + bn[k1] * sn) * nin;
      cv.u[jj] = pkh(x0, x1);
    }
    xfr[kc] = cv.v;
  }
  f32x4 acc[8];
#pragma unroll
  for (int nt = 0; nt < 8; ++nt) {
    acc[nt][0] = 0.f; acc[nt][1] = 0.f; acc[nt][2] = 0.f; acc[nt][3] = 0.f;
  }
#pragma unroll
  for (int nt = 0; nt < 8; ++nt) {
    const f16x8* Wr = (const f16x8*)(Wt0 + (size_t)(nt * 16 + m16) * HID);
#pragma unroll
    for (int kc = 0; kc < 4; ++kc)
      acc[nt] = __builtin_amdgcn_mfma_f32_16x16x32_f16(Wr[kc * 4 + quad], xfr[kc],
                                                       acc[nt], 0, 0, 0);
  }
  if (rvalid) {
    float nov = no_[row];
#pragma unroll
    for (int nt = 0; nt < 8; ++nt) {
      int nb = nt * 16 + quad * 4;
      float4 bv = *(const float4*)&b0[nb];
      float r0 = fmaxf(acc[nt][0] + bv.x, 0.f) * nov;
      float r1 = fmaxf(acc[nt][1] + bv.y, 0.f) * nov;
      float r2 = fmaxf(acc[nt][2] + bv.z, 0.f) * nov;
      float r3 = fmaxf(acc[nt][3] + bv.w, 0.f) * nov;
      uint2 pk;
      pk.x = pkh(r0, r1);
      pk.y = pkh(r2, r3);
      *(uint2*)(h1b + (size_t)row * HID + nb) = pk;
    }
  }
}

// layer-2 aggregate: fp16 gathers, zero-row for invalid slots, packed f32x2 adds
__global__ __launch_bounds__(256) void aggregate_kernel(
    const uint4* __restrict__ hb, const int* __restrict__ row_ofs,
    const int* __restrict__ csr_src, const float* __restrict__ ni_,
    uint4* __restrict__ Ab) {
  int v = (blockIdx.x * blockDim.x + threadIdx.x) >> 6;
  int lane = threadIdx.x & 63;
  if (v >= N_NODES) return;
  int beg = row_ofs[v], end = row_ofs[v + 1];
  int g = lane >> 4, l = lane & 15;
  f32x2 acc2[4];
#pragma unroll
  for (int j = 0; j < 4; ++j) acc2[j] = (f32x2){0.f, 0.f};
  for (int i = beg; i < end; i += 16) {
    int ss[4];
#pragma unroll
    for (int u = 0; u < 4; ++u) {
      int ii = i + 4 * u + g;
      ss[u] = (ii < end) ? csr_src[ii] : N_NODES;  // zero row
    }
    uint4 X[4];
#pragma unroll
    for (int u = 0; u < 4; ++u) X[u] = hb[(size_t)ss[u] * 16 + l];
#pragma unroll
    for (int u = 0; u < 4; ++u) {
      acc2[0] += unpkh(X[u].x);
      acc2[1] += unpkh(X[u].y);
      acc2[2] += unpkh(X[u].z);
      acc2[3] += unpkh(X[u].w);
    }
  }
#pragma unroll
  for (int j = 0; j < 4; ++j) {
    acc2[j][0] += __shfl_xor(acc2[j][0], 16, 64);
    acc2[j][0] += __shfl_xor(acc2[j][0], 32, 64);
    acc2[j][1] += __shfl_xor(acc2[j][1], 16, 64);
    acc2[j][1] += __shfl_xor(acc2[j][1], 32, 64);
  }
  if (g == 0) {
    float n = ni_[v];
    uint4 pk;
    pk.x = pkh(acc2[0][0] * n, acc2[0][1] * n);
    pk.y = pkh(acc2[1][0] * n, acc2[1][1] * n);
    pk.z = pkh(acc2[2][0] * n, acc2[2][1] * n);
    pk.w = pkh(acc2[3][0] * n, acc2[3][1] * n);
    Ab[(size_t)v * 16 + l] = pk;
  }
}

// fused layer-2 GEMM + output GEMM via MFMA (fp16); epilogue adds 0.5*b1 so the
// edge kernel sees y_s + y_d = edge_h @ W1 + b1 with no bias work.
__global__ __launch_bounds__(256) void gemm_dual_mfma(
    const short* __restrict__ Ab, const short* __restrict__ Wt0,
    const float* __restrict__ b0, const short* __restrict__ Wt1,
    const float* __restrict__ b1o, short* __restrict__ yb, int nrows) {
  __shared__ short T1s[4][16 * TP];
  int t = threadIdx.x;
  int w = t >> 6, lane = t & 63;
  int m16 = lane & 15, quad = lane >> 4;
  int v0 = blockIdx.x * 64;
  int row = v0 + w * 16 + m16;
  bool rvalid = row < nrows;
  int rc = rvalid ? row : (nrows - 1);

  f16x8 xfr[4];
  {
    const f16x8* Ar = (const f16x8*)(Ab + (size_t)rc * HID);
#pragma unroll
    for (int kc = 0; kc < 4; ++kc) xfr[kc] = Ar[kc * 4 + quad];
  }
  f32x4 acc[8];
#pragma unroll
  for (int nt = 0; nt < 8; ++nt) {
    acc[nt][0] = 0.f; acc[nt][1] = 0.f; acc[nt][2] = 0.f; acc[nt][3] = 0.f;
  }
#pragma unroll
  for (int nt = 0; nt < 8; ++nt) {
    const f16x8* Wr = (const f16x8*)(Wt0 + (size_t)(nt * 16 + m16) * HID);
#pragma unroll
    for (int kc = 0; kc < 4; ++kc)
      acc[nt] = __builtin_amdgcn_mfma_f32_16x16x32_f16(Wr[kc * 4 + quad], xfr[kc],
                                                       acc[nt], 0, 0, 0);
  }
  short* T1w = &T1s[w][0];
#pragma unroll
  for (int nt = 0; nt < 8; ++nt) {
    int nb = nt * 16 + quad * 4;
    float4 bv = *(const float4*)&b0[nb];
    float r0 = fmaxf(acc[nt][0] + bv.x, 0.f);
    float r1 = fmaxf(acc[nt][1] + bv.y, 0.f);
    float r2 = fmaxf(acc[nt][2] + bv.z, 0.f);
    float r3 = fmaxf(acc[nt][3] + bv.w, 0.f);
    uint2 pk;
    pk.x = pkh(r0, r1);
    pk.y = pkh(r2, r3);
    *(uint2*)&T1w[m16 * TP + nb] = pk;
    acc[nt][0] = 0.f; acc[nt][1] = 0.f; acc[nt][2] = 0.f; acc[nt][3] = 0.f;
  }
  __syncthreads();
  f16x8 tfr[4];
#pragma unroll
  for (int kc = 0; kc < 4; ++kc)
    tfr[kc] = *(const f16x8*)&T1w[m16 * TP + kc * 32 + quad * 8];
#pragma unroll
  for (int nt = 0; nt < 8; ++nt) {
    const f16x8* Wr = (const f16x8*)(Wt1 + (size_t)(nt * 16 + m16) * HID);
#pragma unroll
    for (int kc = 0; kc < 4; ++kc)
      acc[nt] = __builtin_amdgcn_mfma_f32_16x16x32_f16(Wr[kc * 4 + quad], tfr[kc],
                                                       acc[nt], 0, 0, 0);
  }
  if (rvalid) {
#pragma unroll
    for (int nt = 0; nt < 8; ++nt) {
      int nb = nt * 16 + quad * 4;
      float4 bv = *(const float4*)&b1o[nb];
      uint2 pk;
      pk.x = pkh(acc[nt][0] + 0.5f * bv.x, acc[nt][1] + 0.5f * bv.y);
      pk.y = pkh(acc[nt][2] + 0.5f * bv.z, acc[nt][3] + 0.5f * bv.w);
      *(uint2*)(yb + (size_t)row * HID + nb) = pk;
    }
  }
}

// edge output via MFMA (round-4 form): wave handles 64 edges (4 groups of 16).
// Lane (m16=edge, quad=k-chunk): loads one uint4 (8 fp16) of y[src] and y[dst];
// 4 quads/edge share one 64B line -> 4 line-lookups/edge. relu(ys+yd) via
// v_pk_add/v_pk_max feeds the MFMA A-fragment, B = w2 replicated across cols.
__global__ __launch_bounds__(256) void edge_out_mfma(
    const int* __restrict__ csr_src, const int* __restrict__ csr_dst,
    const int* __restrict__ csr_eid, const short* __restrict__ yb,
    const short* __restrict__ w2h16, const float* __restrict__ b2,
    float* __restrict__ out) {
  int t = threadIdx.x;
  int wv = (blockIdx.x * 256 + t) >> 6;  // global wave id
  int lane = t & 63;
  int m16 = lane & 15, quad = lane >> 4;
  int e0 = wv * 64;
  if (e0 >= N_EDGES) return;
  float ob2 = b2[0];

  f16x8 bfr[4];
#pragma unroll
  for (int kb = 0; kb < 4; ++kb)
    bfr[kb] = *(const f16x8*)(w2h16 + kb * 32 + quad * 8);

#pragma unroll
  for (int g = 0; g < 4; ++g) {
    int e = e0 + g * 16 + m16;
    int s = csr_src[e], d = csr_dst[e];
    const short* ys = yb + (size_t)s * HID + quad * 8;
    const short* yd = yb + (size_t)d * HID + quad * 8;
    f32x4 acc = {0.f, 0.f, 0.f, 0.f};
#pragma unroll
    for (int kb = 0; kb < 4; ++kb) {
      uint4 a = *(const uint4*)(ys + kb * 32);
      uint4 b = *(const uint4*)(yd + kb * 32);
      union { uint4 u; f16x8 v; } r;
      r.u.x = hrelu_add(a.x, b.x);
      r.u.y = hrelu_add(a.y, b.y);
      r.u.z = hrelu_add(a.z, b.z);
      r.u.w = hrelu_add(a.w, b.w);
      acc = __builtin_amdgcn_mfma_f32_16x16x32_f16(r.v, bfr[kb], acc, 0, 0, 0);
    }
    if (m16 == 0) {
      int eb = e0 + g * 16 + quad * 4;
#pragma unroll
      for (int r = 0; r < 4; ++r) {
        out[csr_eid[eb + r]] = acc[r] + ob2;
      }
    }
  }
}

extern "C" void kernel_launch(void* const* d_in, const int* in_sizes, int n_in,
                              void* d_out, int out_size, void* d_ws, size_t ws_size,
                              hipStream_t stream) {
  const float* node_feats = (const float*)d_in[1];
  const int*   src        = (const int*)d_in[2];
  const int*   dst        = (const int*)d_in[3];
  const float* W_nemb     = (const float*)d_in[6];
  const float* b_nemb     = (const float*)d_in[7];
  const float* gnn_W      = (const float*)d_in[8];
  const float* gnn_b      = (const float*)d_in[9];
  const float* out_W1     = (const float*)d_in[10];
  const float* out_b1     = (const float*)d_in[11];
  const float* out_W2     = (const float*)d_in[12];
  const float* out_b2     = (const float*)d_in[13];
  float* out = (float*)d_out;

  size_t off = 0;
  char* base = (char*)d_ws;
  auto alloc = [&](size_t nbytes) -> char* {
    off = (off + 255) & ~(size_t)255;
    char* p = base + off;
    off += nbytes;
    return p;
  };
  int*    part_d   = (int*)alloc((size_t)P1G * NB * 4);
  int*    part_s   = (int*)alloc((size_t)P1G * NB * 4);
  int*    bofs_d   = (int*)alloc((NB + 1) * 4);
  int*    bofs_s   = (int*)alloc((NB + 1) * 4);
  int*    cur_d    = (int*)alloc(NB * 4);
  int*    cur_s    = (int*)alloc(NB * 4);
  float*  norm_out = (float*)alloc(N_NODES * 4);
  float*  norm_in  = (float*)alloc(N_NODES * 4);
  int*    row_ofs  = (int*)alloc((N_NODES + 1) * 4);
  int*    csr_src  = (int*)alloc((size_t)N_EDGES * 4);
  int*    csr_eid  = (int*)alloc((size_t)N_EDGES * 4);
  int*    csr_dst  = (int*)alloc((size_t)N_EDGES * 4);
  float4* agg4     = (float4*)alloc((size_t)N_NODES * 16);
  float*  sno      = (float*)alloc(N_NODES * 4);
  short*  Wta      = (short*)alloc((size_t)HID * HID * 2);  // fp16 W_l1^T
  short*  Wtb      = (short*)alloc((size_t)HID * HID * 2);  // fp16 W_l2^T
  short*  Wtc      = (short*)alloc((size_t)HID * HID * 2);  // fp16 out_W1^T
  unsigned* w2h    = (unsigned*)alloc(64 * 4);              // fp16 out_W2 packed
  short*  h1b      = (short*)alloc((size_t)(N_NODES + 1) * HID * 2);  // +zero row
  short*  Ab       = (short*)alloc((size_t)N_NODES * HID * 2);
  short*  ybs      = (short*)alloc((size_t)N_NODES * HID * 2);
  int2*   sdst     = (int2*)Ab;    // staging alias, consumed by p45 before Ab written
  int*    ssrc     = (int*)ybs;    // staging alias, consumed by p45 before yb written
  (void)ws_size; (void)n_in; (void)in_sizes; (void)out_size;

  p1_hist_kernel<<<P1G, 256, 0, stream>>>(src, dst, part_d, part_s);
  p2_scan_prep_kernel<<<65, 256, 0, stream>>>(
      part_d, part_s, bofs_d, bofs_s, cur_d, cur_s,
      gnn_W, gnn_W + (size_t)HID * HID, out_W1, out_W2,
      Wta, Wtb, Wtc, w2h, h1b + (size_t)N_NODES * HID);
  p3_scatter_both_kernel<<<(N_EDGES + 2047) / 2048, 256, 0, stream>>>(
      src, dst, cur_d, cur_s, sdst, ssrc);
  p45_kernel<<<2 * NB, 256, 0, stream>>>(
      sdst, bofs_d, row_ofs, norm_in, csr_src, csr_eid, csr_dst,
      ssrc, bofs_s, norm_out);

  agg4_kernel<<<(N_NODES * 16 + 255) / 256, 256, 0, stream>>>(
      (const float4*)node_feats, norm_out, csr_src, row_ofs, agg4, sno);
  gemm_l1_mfma<<<(N_NODES + 63) / 64, 256, 0, stream>>>(
      agg4, sno, norm_in, norm_out, W_nemb, b_nemb, Wta, gnn_b, h1b, N_NODES);

  aggregate_kernel<<<(N_NODES * 64 + 255) / 256, 256, 0, stream>>>(
      (const uint4*)h1b, row_ofs, csr_src, norm_in, (uint4*)Ab);

  gemm_dual_mfma<<<(N_NODES + 63) / 64, 256, 0, stream>>>(
      Ab, Wtb, gnn_b + HID, Wtc, out_b1, ybs, N_NODES);

  edge_out_mfma<<<(N_EDGES / 64 + 3) / 4, 256, 0, stream>>>(
      csr_src, csr_dst, csr_eid, ybs, (const short*)w2h, out_b2, out);
}

// Round 12
// 301.858 us; speedup vs baseline: 1.0703x; 1.0203x over previous
//
#include <hip/hip_runtime.h>

#define N_NODES 50000
#define N_EDGES 800000
#define HID 128
#define NB 256   // node buckets
#define NPB 196  // nodes per bucket
#define TP 136   // T1 LDS row stride in shorts

typedef __attribute__((ext_vector_type(8))) _Float16 f16x8;
typedef __attribute__((ext_vector_type(2))) _Float16 h2v;
typedef __attribute__((ext_vector_type(2))) __fp16 fp16v2;
typedef __attribute__((ext_vector_type(4))) float f32x4;
typedef __attribute__((ext_vector_type(2))) float f32x2;

__device__ __forceinline__ unsigned pkh(float a, float b) {
  union { fp16v2 h; unsigned u; } c;
  c.h = __builtin_amdgcn_cvt_pkrtz(a, b);
  return c.u;
}
__device__ __forceinline__ h2v u2h(unsigned u) {
  union { unsigned u; h2v h; } c;
  c.u = u;
  return c.h;
}
__device__ __forceinline__ f32x2 unpkh(unsigned u) {
  h2v h = u2h(u);
  f32x2 r;
  r[0] = (float)h[0];
  r[1] = (float)h[1];
  return r;
}
__device__ __forceinline__ short f2hs(float f) {
  union { _Float16 h; short s; } c;
  c.h = (_Float16)f;
  return c.s;
}
// packed fp16: relu(a+b), returns packed pair (v_pk_add_f16 + v_pk_max_f16)
__device__ __forceinline__ unsigned hrelu_add(unsigned a, unsigned b) {
  h2v r = u2h(a) + u2h(b);
  h2v z = {(_Float16)0.f, (_Float16)0.f};
  r = __builtin_elementwise_max(r, z);
  union { h2v h; unsigned u; } c;
  c.h = r;
  return c.u;
}

// ================= bucketed CSR build =================

__global__ __launch_bounds__(256) void p1_hist_kernel(
    const int* __restrict__ src, const int* __restrict__ dst,
    int* __restrict__ bcnt_d, int* __restrict__ bcnt_s) {
  __shared__ int hd[NB], hs[NB];
  int t = threadIdx.x;
  hd[t] = 0; hs[t] = 0;
  __syncthreads();
  for (int e = blockIdx.x * 256 + t; e < N_EDGES; e += gridDim.x * 256) {
    atomicAdd(&hd[dst[e] / NPB], 1);
    atomicAdd(&hs[src[e] / NPB], 1);
  }
  __syncthreads();
  if (hd[t]) atomicAdd(&bcnt_d[t], hd[t]);
  if (hs[t]) atomicAdd(&bcnt_s[t], hs[t]);
}

// block 0: dual scan.  blocks 1..64: fp16 weight transposes + w2h pack + h1b zero row
__global__ void p2_scan_prep_kernel(
    const int* __restrict__ bcnt_d, const int* __restrict__ bcnt_s,
    int* __restrict__ bofs_d, int* __restrict__ bofs_s,
    int* __restrict__ cur_d, int* __restrict__ cur_s,
    const float* __restrict__ Wa, const float* __restrict__ Wb,
    const float* __restrict__ Wc, const float* __restrict__ w2f,
    short* __restrict__ Wta, short* __restrict__ Wtb, short* __restrict__ Wtc,
    unsigned* __restrict__ w2h, short* __restrict__ h1bz) {
  int b = blockIdx.x;
  if (b > 0) {
    int t = (b - 1) * 256 + threadIdx.x;
    if (t < HID * HID) {
      int k = t >> 7, n = t & 127;
      Wta[n * HID + k] = f2hs(Wa[t]);
      Wtb[n * HID + k] = f2hs(Wb[t]);
      Wtc[n * HID + k] = f2hs(Wc[t]);
    }
    if (b == 1) {
      int t0 = threadIdx.x;
      if (t0 < 64) {
        w2h[t0] = pkh(w2f[2 * t0], w2f[2 * t0 + 1]);
      } else if (t0 < 128) {
        ((unsigned*)h1bz)[t0 - 64] = 0u;
      }
    }
    return;
  }
  __shared__ int s[NB];
  int t = threadIdx.x;
  int v = bcnt_d[t];
  s[t] = v;
  __syncthreads();
  for (int o = 1; o < NB; o <<= 1) {
    int x = (t >= o) ? s[t - o] : 0;
    __syncthreads();
    s[t] += x;
    __syncthreads();
  }
  int ofs = s[t] - v;
  bofs_d[t] = ofs; cur_d[t] = ofs;
  if (t == NB - 1) bofs_d[NB] = s[t];
  __syncthreads();
  v = bcnt_s[t];
  s[t] = v;
  __syncthreads();
  for (int o = 1; o < NB; o <<= 1) {
    int x = (t >= o) ? s[t - o] : 0;
    __syncthreads();
    s[t] += x;
    __syncthreads();
  }
  ofs = s[t] - v;
  bofs_s[t] = ofs; cur_s[t] = ofs;
  if (t == NB - 1) bofs_s[NB] = s[t];
}

// fused dst+src scatter: one pass over edges, two LDS histograms
__global__ __launch_bounds__(256) void p3_scatter_both_kernel(
    const int* __restrict__ src, const int* __restrict__ dst,
    int* __restrict__ cur_d, int* __restrict__ cur_s,
    int2* __restrict__ sdst, int* __restrict__ ssrc) {
  __shared__ int bcd[NB], bbd[NB], bcs[NB], bbs[NB];
  int t = threadIdx.x;
  int base = blockIdx.x * 2048;
  bcd[t] = 0; bcs[t] = 0;
  __syncthreads();
  int mybd[8], myrd[8], mys[8], myp[8], mybs[8], myrs[8];
#pragma unroll
  for (int u = 0; u < 8; ++u) {
    int e = base + u * 256 + t;
    mybd[u] = -1;
    if (e < N_EDGES) {
      int s = src[e], d = dst[e];
      int bd = d / NPB;
      mybd[u] = bd;
      myrd[u] = atomicAdd(&bcd[bd], 1);
      mys[u] = s;
      myp[u] = ((d - bd * NPB) << 20) | e;
      int bs = s / NPB;
      mybs[u] = bs;
      myrs[u] = atomicAdd(&bcs[bs], 1);
    }
  }
  __syncthreads();
  {
    int cd = bcd[t];
    if (cd) bbd[t] = atomicAdd(&cur_d[t], cd);
    int cs = bcs[t];
    if (cs) bbs[t] = atomicAdd(&cur_s[t], cs);
  }
  __syncthreads();
#pragma unroll
  for (int u = 0; u < 8; ++u) {
    if (mybd[u] >= 0) {
      sdst[bbd[mybd[u]] + myrd[u]] = make_int2(mys[u], myp[u]);
      ssrc[bbs[mybs[u]] + myrs[u]] = mys[u];
    }
  }
}

// merged p4 (CSR build, blocks [0,NB)) + p5 (deg_out, blocks [NB,2NB))
__global__ __launch_bounds__(256) void p45_kernel(
    const int2* __restrict__ sdst, const int* __restrict__ bofs_d,
    int* __restrict__ row_ofs, float* __restrict__ norm_in,
    int* __restrict__ csr_src, int* __restrict__ csr_eid, int* __restrict__ csr_dst,
    const int* __restrict__ ssrc, const int* __restrict__ bofs_s,
    float* __restrict__ norm_out) {
  __shared__ int hc[NB], sc[NB], cur[NB];
  int t = threadIdx.x;
  if (blockIdx.x >= NB) {
    // ---- p5: out-degree ----
    int b = blockIdx.x - NB;
    int base = bofs_s[b], cnt = bofs_s[b + 1] - base;
    int lo = b * NPB;
    hc[t] = 0;
    __syncthreads();
    for (int i = t; i < cnt; i += 256) atomicAdd(&hc[ssrc[base + i] - lo], 1);
    __syncthreads();
    int node = lo + t;
    if (t < NPB && node < N_NODES) {
      int v = hc[t];
      norm_out[node] = rsqrtf((float)(v < 1 ? 1 : v));
    }
    return;
  }
  // ---- p4: CSR ----
  int b = blockIdx.x;
  int base = bofs_d[b], cnt = bofs_d[b + 1] - base;
  hc[t] = 0;
  __syncthreads();
  for (int i = t; i < cnt; i += 256) atomicAdd(&hc[sdst[base + i].y >> 20], 1);
  __syncthreads();
  int v = hc[t];
  sc[t] = v;
  __syncthreads();
  for (int o = 1; o < NB; o <<= 1) {
    int x = (t >= o) ? sc[t - o] : 0;
    __syncthreads();
    sc[t] += x;
    __syncthreads();
  }
  int ofs = sc[t] - v;
  int node = b * NPB + t;
  if (t < NPB && node < N_NODES) {
    row_ofs[node] = base + ofs;
    norm_in[node] = rsqrtf((float)(v < 1 ? 1 : v));
  }
  cur[t] = base + ofs;
  if (b == 0 && t == 0) row_ofs[N_NODES] = N_EDGES;
  __syncthreads();
  for (int i = t; i < cnt; i += 256) {
    int2 e = sdst[base + i];
    int loc = e.y >> 20;
    int pos = atomicAdd(&cur[loc], 1);
    csr_src[pos] = e.x;
    csr_eid[pos] = e.y & 0xFFFFF;
    csr_dst[pos] = b * NPB + loc;
  }
}

// ================= model kernels =================

__global__ __launch_bounds__(256) void agg4_kernel(
    const float4* __restrict__ nf4, const float* __restrict__ no_,
    const int* __restrict__ csr_src, const int* __restrict__ row_ofs,
    float4* __restrict__ agg4, float* __restrict__ sno) {
  int wid = (blockIdx.x * blockDim.x + threadIdx.x) >> 6;
  int lane = threadIdx.x & 63;
  int g = lane >> 4, l = lane & 15;
  int v = wid * 4 + g;
  if (v >= N_NODES) return;
  int beg = row_ofs[v], end = row_ofs[v + 1];
  float ax = 0.f, ay = 0.f, az = 0.f, aw = 0.f, sn = 0.f;
  for (int i = beg + l; i < end; i += 16) {
    int s = csr_src[i];
    float w = no_[s];
    float4 n = nf4[s];
    ax += n.x * w; ay += n.y * w; az += n.z * w; aw += n.w * w;
    sn += w;
  }
#pragma unroll
  for (int o = 1; o < 16; o <<= 1) {
    ax += __shfl_xor(ax, o, 16);
    ay += __shfl_xor(ay, o, 16);
    az += __shfl_xor(az, o, 16);
    aw += __shfl_xor(aw, o, 16);
    sn += __shfl_xor(sn, o, 16);
  }
  if (l == 0) {
    agg4[v] = make_float4(ax, ay, az, aw);
    sno[v] = sn;
  }
}

// layer-1 fully fused via MFMA (fp16): expand 4->128 per-lane in B-frag layout, no LDS.
__global__ __launch_bounds__(256) void gemm_l1_mfma(
    const float4* __restrict__ agg4, const float* __restrict__ sno,
    const float* __restrict__ ni_, const float* __restrict__ no_,
    const float* __restrict__ Wn, const float* __restrict__ bn,
    const short* __restrict__ Wt0, const float* __restrict__ b0,
    short* __restrict__ h1b, int nrows) {
  int t = threadIdx.x;
  int w = t >> 6, lane = t & 63;
  int m16 = lane & 15, quad = lane >> 4;
  int v0 = blockIdx.x * 64;
  int row = v0 + w * 16 + m16;
  bool rvalid = row < nrows;
  int rc = rvalid ? row : (nrows - 1);
  float4 a = agg4[rc];
  float sn = sno[rc], nin = ni_[rc];

  f16x8 xfr[4];
#pragma unroll
  for (int kc = 0; kc < 4; ++kc) {
    union { unsigned u[4]; f16x8 v; } cv;
#pragma unroll
    for (int jj = 0; jj < 4; ++jj) {
      int k0 = kc * 32 + quad * 8 + jj * 2;
      float x0 = (a.x * Wn[k0] + a.y * Wn[HID + k0] + a.z * Wn[2 * HID + k0] +
                  a.w * Wn[3 * HID + k0] + bn[k0] * sn) * nin;
      int k1 = k0 + 1;
      float x1 = (a.x * Wn[k1] + a.y * Wn[HID + k1] + a.z * Wn[2 * HID + k1] +
                  a.w * Wn[3 * HID + k1] + bn[k1] * sn) * nin;
      cv.u[jj] = pkh(x0, x1);
    }
    xfr[kc] = cv.v;
  }
  f32x4 acc[8];
#pragma unroll
  for (int nt = 0; nt < 8; ++nt) {
    acc[nt][0] = 0.f; acc[nt][1] = 0.f; acc[nt][2] = 0.f; acc[nt][3] = 0.f;
  }
#pragma unroll
  for (int nt = 0; nt < 8; ++nt) {
    const f16x8* Wr = (const f16x8*)(Wt0 + (size_t)(nt * 16 + m16) * HID);
#pragma unroll
    for (int kc = 0; kc < 4; ++kc)
      acc[nt] = __builtin_amdgcn_mfma_f32_16x16x32_f16(Wr[kc * 4 + quad], xfr[kc],
                                                       acc[nt], 0, 0, 0);
  }
  if (rvalid) {
    float nov = no_[row];
#pragma unroll
    for (int nt = 0; nt < 8; ++nt) {
      int nb = nt * 16 + quad * 4;
      float4 bv = *(const float4*)&b0[nb];
      float r0 = fmaxf(acc[nt][0] + bv.x, 0.f) * nov;
      float r1 = fmaxf(acc[nt][1] + bv.y, 0.f) * nov;
      float r2 = fmaxf(acc[nt][2] + bv.z, 0.f) * nov;
      float r3 = fmaxf(acc[nt][3] + bv.w, 0.f) * nov;
      uint2 pk;
      pk.x = pkh(r0, r1);
      pk.y = pkh(r2, r3);
      *(uint2*)(h1b + (size_t)row * HID + nb) = pk;
    }
  }
}

// layer-2 aggregate: fp16 gathers, zero-row for invalid slots, packed f32x2 adds
__global__ __launch_bounds__(256) void aggregate_kernel(
    const uint4* __restrict__ hb, const int* __restrict__ row_ofs,
    const int* __restrict__ csr_src, const float* __restrict__ ni_,
    uint4* __restrict__ Ab) {
  int v = (blockIdx.x * blockDim.x + threadIdx.x) >> 6;
  int lane = threadIdx.x & 63;
  if (v >= N_NODES) return;
  int beg = row_ofs[v], end = row_ofs[v + 1];
  int g = lane >> 4, l = lane & 15;
  f32x2 acc2[4];
#pragma unroll
  for (int j = 0; j < 4; ++j) acc2[j] = (f32x2){0.f, 0.f};
  for (int i = beg; i < end; i += 16) {
    int ss[4];
#pragma unroll
    for (int u = 0; u < 4; ++u) {
      int ii = i + 4 * u + g;
      ss[u] = (ii < end) ? csr_src[ii] : N_NODES;  // zero row
    }
    uint4 X[4];
#pragma unroll
    for (int u = 0; u < 4; ++u) X[u] = hb[(size_t)ss[u] * 16 + l];
#pragma unroll
    for (int u = 0; u < 4; ++u) {
      acc2[0] += unpkh(X[u].x);
      acc2[1] += unpkh(X[u].y);
      acc2[2] += unpkh(X[u].z);
      acc2[3] += unpkh(X[u].w);
    }
  }
#pragma unroll
  for (int j = 0; j < 4; ++j) {
    acc2[j][0] += __shfl_xor(acc2[j][0], 16, 64);
    acc2[j][0] += __shfl_xor(acc2[j][0], 32, 64);
    acc2[j][1] += __shfl_xor(acc2[j][1], 16, 64);
    acc2[j][1] += __shfl_xor(acc2[j][1], 32, 64);
  }
  if (g == 0) {
    float n = ni_[v];
    uint4 pk;
    pk.x = pkh(acc2[0][0] * n, acc2[0][1] * n);
    pk.y = pkh(acc2[1][0] * n, acc2[1][1] * n);
    pk.z = pkh(acc2[2][0] * n, acc2[2][1] * n);
    pk.w = pkh(acc2[3][0] * n, acc2[3][1] * n);
    Ab[(size_t)v * 16 + l] = pk;
  }
}

// fused layer-2 GEMM + output GEMM via MFMA (fp16); epilogue adds 0.5*b1 so the
// edge kernel sees y_s + y_d = edge_h @ W1 + b1 with no bias work.
__global__ __launch_bounds__(256) void gemm_dual_mfma(
    const short* __restrict__ Ab, const short* __restrict__ Wt0,
    const float* __restrict__ b0, const short* __restrict__ Wt1,
    const float* __restrict__ b1o, short* __restrict__ yb, int nrows) {
  __shared__ short T1s[4][16 * TP];
  int t = threadIdx.x;
  int w = t >> 6, lane = t & 63;
  int m16 = lane & 15, quad = lane >> 4;
  int v0 = blockIdx.x * 64;
  int row = v0 + w * 16 + m16;
  bool rvalid = row < nrows;
  int rc = rvalid ? row : (nrows - 1);

  f16x8 xfr[4];
  {
    const f16x8* Ar = (const f16x8*)(Ab + (size_t)rc * HID);
#pragma unroll
    for (int kc = 0; kc < 4; ++kc) xfr[kc] = Ar[kc * 4 + quad];
  }
  f32x4 acc[8];
#pragma unroll
  for (int nt = 0; nt < 8; ++nt) {
    acc[nt][0] = 0.f; acc[nt][1] = 0.f; acc[nt][2] = 0.f; acc[nt][3] = 0.f;
  }
#pragma unroll
  for (int nt = 0; nt < 8; ++nt) {
    const f16x8* Wr = (const f16x8*)(Wt0 + (size_t)(nt * 16 + m16) * HID);
#pragma unroll
    for (int kc = 0; kc < 4; ++kc)
      acc[nt] = __builtin_amdgcn_mfma_f32_16x16x32_f16(Wr[kc * 4 + quad], xfr[kc],
                                                       acc[nt], 0, 0, 0);
  }
  short* T1w = &T1s[w][0];
#pragma unroll
  for (int nt = 0; nt < 8; ++nt) {
    int nb = nt * 16 + quad * 4;
    float4 bv = *(const float4*)&b0[nb];
    float r0 = fmaxf(acc[nt][0] + bv.x, 0.f);
    float r1 = fmaxf(acc[nt][1] + bv.y, 0.f);
    float r2 = fmaxf(acc[nt][2] + bv.z, 0.f);
    float r3 = fmaxf(acc[nt][3] + bv.w, 0.f);
    uint2 pk;
    pk.x = pkh(r0, r1);
    pk.y = pkh(r2, r3);
    *(uint2*)&T1w[m16 * TP + nb] = pk;
    acc[nt][0] = 0.f; acc[nt][1] = 0.f; acc[nt][2] = 0.f; acc[nt][3] = 0.f;
  }
  __syncthreads();
  f16x8 tfr[4];
#pragma unroll
  for (int kc = 0; kc < 4; ++kc)
    tfr[kc] = *(const f16x8*)&T1w[m16 * TP + kc * 32 + quad * 8];
#pragma unroll
  for (int nt = 0; nt < 8; ++nt) {
    const f16x8* Wr = (const f16x8*)(Wt1 + (size_t)(nt * 16 + m16) * HID);
#pragma unroll
    for (int kc = 0; kc < 4; ++kc)
      acc[nt] = __builtin_amdgcn_mfma_f32_16x16x32_f16(Wr[kc * 4 + quad], tfr[kc],
                                                       acc[nt], 0, 0, 0);
  }
  if (rvalid) {
#pragma unroll
    for (int nt = 0; nt < 8; ++nt) {
      int nb = nt * 16 + quad * 4;
      float4 bv = *(const float4*)&b1o[nb];
      uint2 pk;
      pk.x = pkh(acc[nt][0] + 0.5f * bv.x, acc[nt][1] + 0.5f * bv.y);
      pk.y = pkh(acc[nt][2] + 0.5f * bv.z, acc[nt][3] + 0.5f * bv.w);
      *(uint2*)(yb + (size_t)row * HID + nb) = pk;
    }
  }
}

// edge output via MFMA: wave handles 64 edges (4 groups of 16).
// Lane (m16=edge, quad=k-chunk): loads one uint4 (8 fp16) of y[src] and y[dst];
// the 4 quads of an edge share one 64B line -> coalescer merges -> 4 line-lookups
// per edge (optimal). relu(ys+yd) via v_pk_add/v_pk_max feeds the A-fragment of
// mfma_f32_16x16x32_f16 with B = w2 replicated across 16 cols. No shuffles.
__global__ __launch_bounds__(256) void edge_out_mfma(
    const int* __restrict__ csr_src, const int* __restrict__ csr_dst,
    const int* __restrict__ csr_eid, const short* __restrict__ yb,
    const short* __restrict__ w2h16, const float* __restrict__ b2,
    float* __restrict__ out) {
  int t = threadIdx.x;
  int wv = (blockIdx.x * 256 + t) >> 6;  // global wave id
  int lane = t & 63;
  int m16 = lane & 15, quad = lane >> 4;
  int e0 = wv * 64;
  if (e0 >= N_EDGES) return;
  float ob2 = b2[0];

  // B-fragments: w2[k] replicated across all 16 output cols.
  f16x8 bfr[4];
#pragma unroll
  for (int kb = 0; kb < 4; ++kb)
    bfr[kb] = *(const f16x8*)(w2h16 + kb * 32 + quad * 8);

#pragma unroll
  for (int g = 0; g < 4; ++g) {
    int e = e0 + g * 16 + m16;
    int s = csr_src[e], d = csr_dst[e];
    const short* ys = yb + (size_t)s * HID + quad * 8;
    const short* yd = yb + (size_t)d * HID + quad * 8;
    f32x4 acc = {0.f, 0.f, 0.f, 0.f};
#pragma unroll
    for (int kb = 0; kb < 4; ++kb) {
      uint4 a = *(const uint4*)(ys + kb * 32);
      uint4 b = *(const uint4*)(yd + kb * 32);
      union { uint4 u; f16x8 v; } r;
      r.u.x = hrelu_add(a.x, b.x);
      r.u.y = hrelu_add(a.y, b.y);
      r.u.z = hrelu_add(a.z, b.z);
      r.u.w = hrelu_add(a.w, b.w);
      acc = __builtin_amdgcn_mfma_f32_16x16x32_f16(r.v, bfr[kb], acc, 0, 0, 0);
    }
    // D col = lane&15, row = (lane>>4)*4 + reg. All cols equal; use col 0.
    if (m16 == 0) {
      int eb = e0 + g * 16 + quad * 4;
#pragma unroll
      for (int r = 0; r < 4; ++r) {
        out[csr_eid[eb + r]] = acc[r] + ob2;
      }
    }
  }
}

extern "C" void kernel_launch(void* const* d_in, const int* in_sizes, int n_in,
                              void* d_out, int out_size, void* d_ws, size_t ws_size,
                              hipStream_t stream) {
  const float* node_feats = (const float*)d_in[1];
  const int*   src        = (const int*)d_in[2];
  const int*   dst        = (const int*)d_in[3];
  const float* W_nemb     = (const float*)d_in[6];
  const float* b_nemb     = (const float*)d_in[7];
  const float* gnn_W      = (const float*)d_in[8];
  const float* gnn_b      = (const float*)d_in[9];
  const float* out_W1     = (const float*)d_in[10];
  const float* out_b1     = (const float*)d_in[11];
  const float* out_W2     = (const float*)d_in[12];
  const float* out_b2     = (const float*)d_in[13];
  float* out = (float*)d_out;

  size_t off = 0;
  char* base = (char*)d_ws;
  auto alloc = [&](size_t nbytes) -> char* {
    off = (off + 255) & ~(size_t)255;
    char* p = base + off;
    off += nbytes;
    return p;
  };
  int*    bcnt2    = (int*)alloc(2 * NB * 4);
  int*    bofs_d   = (int*)alloc((NB + 1) * 4);
  int*    bofs_s   = (int*)alloc((NB + 1) * 4);
  int*    cur_d    = (int*)alloc(NB * 4);
  int*    cur_s    = (int*)alloc(NB * 4);
  float*  norm_out = (float*)alloc(N_NODES * 4);
  float*  norm_in  = (float*)alloc(N_NODES * 4);
  int*    row_ofs  = (int*)alloc((N_NODES + 1) * 4);
  int*    csr_src  = (int*)alloc((size_t)N_EDGES * 4);
  int*    csr_eid  = (int*)alloc((size_t)N_EDGES * 4);
  int*    csr_dst  = (int*)alloc((size_t)N_EDGES * 4);
  float4* agg4     = (float4*)alloc((size_t)N_NODES * 16);
  float*  sno      = (float*)alloc(N_NODES * 4);
  short*  Wta      = (short*)alloc((size_t)HID * HID * 2);  // fp16 W_l1^T
  short*  Wtb      = (short*)alloc((size_t)HID * HID * 2);  // fp16 W_l2^T
  short*  Wtc      = (short*)alloc((size_t)HID * HID * 2);  // fp16 out_W1^T
  unsigned* w2h    = (unsigned*)alloc(64 * 4);              // fp16 out_W2 packed
  short*  h1b      = (short*)alloc((size_t)(N_NODES + 1) * HID * 2);  // +zero row
  short*  Ab       = (short*)alloc((size_t)N_NODES * HID * 2);
  short*  ybs      = (short*)alloc((size_t)N_NODES * HID * 2);
  int2*   sdst     = (int2*)Ab;    // staging alias, consumed by p45 before Ab written
  int*    ssrc     = (int*)ybs;    // staging alias, consumed by p45 before yb written
  int*    bcnt_d   = bcnt2;
  int*    bcnt_s   = bcnt2 + NB;
  (void)ws_size; (void)n_in; (void)in_sizes; (void)out_size;

  (void)hipMemsetAsync(bcnt2, 0, 2 * NB * 4, stream);
  p1_hist_kernel<<<128, 256, 0, stream>>>(src, dst, bcnt_d, bcnt_s);
  p2_scan_prep_kernel<<<65, 256, 0, stream>>>(
      bcnt_d, bcnt_s, bofs_d, bofs_s, cur_d, cur_s,
      gnn_W, gnn_W + (size_t)HID * HID, out_W1, out_W2,
      Wta, Wtb, Wtc, w2h, h1b + (size_t)N_NODES * HID);
  p3_scatter_both_kernel<<<(N_EDGES + 2047) / 2048, 256, 0, stream>>>(
      src, dst, cur_d, cur_s, sdst, ssrc);
  p45_kernel<<<2 * NB, 256, 0, stream>>>(
      sdst, bofs_d, row_ofs, norm_in, csr_src, csr_eid, csr_dst,
      ssrc, bofs_s, norm_out);

  agg4_kernel<<<(N_NODES * 16 + 255) / 256, 256, 0, stream>>>(
      (const float4*)node_feats, norm_out, csr_src, row_ofs, agg4, sno);
  gemm_l1_mfma<<<(N_NODES + 63) / 64, 256, 0, stream>>>(
      agg4, sno, norm_in, norm_out, W_nemb, b_nemb, Wta, gnn_b, h1b, N_NODES);

  aggregate_kernel<<<(N_NODES * 64 + 255) / 256, 256, 0, stream>>>(
      (const uint4*)h1b, row_ofs, csr_src, norm_in, (uint4*)Ab);

  gemm_dual_mfma<<<(N_NODES + 63) / 64, 256, 0, stream>>>(
      Ab, Wtb, gnn_b + HID, Wtc, out_b1, ybs, N_NODES);

  edge_out_mfma<<<(N_EDGES / 64 + 3) / 4, 256, 0, stream>>>(
      csr_src, csr_dst, csr_eid, ybs, (const short*)w2h, out_b2, out);
}